// Round 3
// baseline (11.100 us; speedup 1.0000x reference)
//
#include <hip/hip_runtime.h>

// Vibrato — reference's jnp.take uses ABSOLUTE indices idx[t,d] = (int)(v+d), d=0..219,
// v = depth*lfo(t) in [0,5], into delayed = [220 zeros | audio[:N-220]].
// Only idx >= 220 hits nonzero data, i.e. only d = 215..219 can contribute, and the
// contributing set is audio[0..k-1] with k = (int)(v + 219) - 219   (0..5).
//   (valid since RN(v+d+1) = RN(v+d)+1 exactly within the [128,256) binade)
// out[b,c,t] = (audio[b,c,0] + ... + audio[b,c,k-1]) / 220, summed ascending (= ref order).
//
// Bit-exact chain kept from the passing round-1 kernel:
//   ts    = f32 division t/44100.0f           (IEEE CR)
//   theta = fl32(fl32(2pi)*rate) * ts
//   s     = (float)sin((double)theta)          (CR f32 sin)
//   v     = depth * fl32(0.5*(1+s))
//   sums:  sequential ascending adds, then /220.0f division.

typedef float f32x4 __attribute__((ext_vector_type(4)));  // native vector for nontemporal builtin

__global__ __launch_bounds__(256) void Vibrato_90142773608915_kernel(
    const float* __restrict__ audio,   // [4, N] flattened (B=2, C=2)
    const float* __restrict__ depth_p, // scalar
    const float* __restrict__ rate_p,  // scalar
    float* __restrict__ out,           // [4, N]
    int N)                             // divisible by 4
{
    int tid = blockIdx.x * blockDim.x + threadIdx.x;
    int t0 = tid * 4;
    if (t0 >= N) return;

    const float depth = depth_p[0];
    const float rate  = rate_p[0];
    const float TWO_PI_F = 0x1.921fb6p+2f;     // fl32(2*pi)
    const float w = TWO_PI_F * rate;

    // Prefix table r[k][c] = (audio[c][0]+...+audio[c][k-1]) / 220, k = 0..5.
    // Addresses are thread-uniform -> scalar loads; all unrolled -> registers.
    float r[6][4];
    #pragma unroll
    for (int c = 0; c < 4; ++c) {
        float p = 0.0f;
        r[0][c] = 0.0f;
        #pragma unroll
        for (int j = 0; j < 5; ++j) {
            p += audio[(size_t)c * N + j];     // sequential ascending = ref order
            r[j + 1][c] = p / 220.0f;          // IEEE division, same as round-1
        }
    }

    f32x4 o0, o1, o2, o3;

    #pragma unroll
    for (int i = 0; i < 4; ++i) {
        int t = t0 + i;
        float ts    = (float)t / 44100.0f;     // exact: t < 2^24, CR division
        float theta = w * ts;
        float s     = (float)sin((double)theta);
        float lfo   = 0.5f * (1.0f + s);
        float v     = depth * lfo;             // [0, 5]
        int   k     = (int)(v + 219.0f) - 219; // window length, 0..5

        float res0 = r[0][0], res1 = r[0][1], res2 = r[0][2], res3 = r[0][3];
        #pragma unroll
        for (int kk = 1; kk <= 5; ++kk) {
            bool ge = (k >= kk);
            res0 = ge ? r[kk][0] : res0;
            res1 = ge ? r[kk][1] : res1;
            res2 = ge ? r[kk][2] : res2;
            res3 = ge ? r[kk][3] : res3;
        }
        o0[i] = res0; o1[i] = res1; o2[i] = res2; o3[i] = res3;
    }

    // N divisible by 4 -> 16B-aligned float4 stores per channel
    __builtin_nontemporal_store(o0, (f32x4*)(out + t0));
    __builtin_nontemporal_store(o1, (f32x4*)(out + (size_t)N + t0));
    __builtin_nontemporal_store(o2, (f32x4*)(out + 2 * (size_t)N + t0));
    __builtin_nontemporal_store(o3, (f32x4*)(out + 3 * (size_t)N + t0));
}

extern "C" void kernel_launch(void* const* d_in, const int* in_sizes, int n_in,
                              void* d_out, int out_size, void* d_ws, size_t ws_size,
                              hipStream_t stream) {
    const float* audio = (const float*)d_in[0];
    const float* depth = (const float*)d_in[1];
    const float* rate  = (const float*)d_in[2];
    float* out = (float*)d_out;

    int N = in_sizes[0] / 4;               // B*C = 4 channels; N = 220500 (divisible by 4)
    int n_threads = N / 4;                 // 55125
    int threads = 256;
    int blocks = (n_threads + threads - 1) / threads;  // 216
    Vibrato_90142773608915_kernel<<<blocks, threads, 0, stream>>>(audio, depth, rate, out, N);
}

// Round 4
// 10.200 us; speedup vs baseline: 1.0883x; 1.0883x over previous
//
#include <hip/hip_runtime.h>

// Vibrato — reference's jnp.take uses ABSOLUTE indices idx[t,d] = (int)(v+d), d=0..219,
// v = depth*lfo(t) in [0,5], into delayed = [220 zeros | audio[:N-220]].
// Only d=215..219 can hit nonzero data; contributing set is audio[0..k-1] with
// k = (int)(v + 219) - 219  (0..5), valid since RN(v+d+1) = RN(v+d)+1 within [128,256).
// out[b,c,t] = (audio[b,c,0]+...+audio[b,c,k-1]) / 220, ascending adds (= ref order).
//
// Bit-exact chain (identical to the two passing rounds):
//   ts    = f32 division t/44100.0f   (IEEE CR; t < 2^24 exact)
//   theta = fl32(fl32(2pi)*rate) * ts
//   s     = (float)sin((double)theta) (CR f32 sin)
//   v     = depth * fl32(0.5*(1+s))
//   result: sequential ascending adds then /220.0f.
//
// Shape: 1 timestep/thread (round-1 shape — best measured), k-collapse select
// from a uniform prefix table, nontemporal scalar stores.

__global__ __launch_bounds__(256) void Vibrato_90142773608915_kernel(
    const float* __restrict__ audio,   // [4, N] flattened (B=2, C=2)
    const float* __restrict__ depth_p, // scalar
    const float* __restrict__ rate_p,  // scalar
    float* __restrict__ out,           // [4, N]
    int N)
{
    int t = blockIdx.x * blockDim.x + threadIdx.x;
    if (t >= N) return;

    const float depth = depth_p[0];
    const float rate  = rate_p[0];
    const float TWO_PI_F = 0x1.921fb6p+2f;     // fl32(2*pi)
    const float w = TWO_PI_F * rate;

    // Uniform prefix table r[k][c] = (audio[c][0]+..+audio[c][k-1]) / 220, k=0..5.
    // Thread-uniform addresses -> scalar loads; fully unrolled -> registers.
    float r[6][4];
    #pragma unroll
    for (int c = 0; c < 4; ++c) {
        float p = 0.0f;
        r[0][c] = 0.0f;
        #pragma unroll
        for (int j = 0; j < 5; ++j) {
            p += audio[(size_t)c * N + j];     // ascending adds = ref order
            r[j + 1][c] = p / 220.0f;          // IEEE division, same as passing rounds
        }
    }

    float ts    = (float)t / 44100.0f;
    float theta = w * ts;
    float s     = (float)sin((double)theta);
    float lfo   = 0.5f * (1.0f + s);
    float v     = depth * lfo;                 // [0, 5]
    int   k     = (int)(v + 219.0f) - 219;     // window length, 0..5

    float res0 = r[0][0], res1 = r[0][1], res2 = r[0][2], res3 = r[0][3];
    #pragma unroll
    for (int kk = 1; kk <= 5; ++kk) {
        bool ge = (k >= kk);
        res0 = ge ? r[kk][0] : res0;
        res1 = ge ? r[kk][1] : res1;
        res2 = ge ? r[kk][2] : res2;
        res3 = ge ? r[kk][3] : res3;
    }

    __builtin_nontemporal_store(res0, out + t);
    __builtin_nontemporal_store(res1, out + (size_t)N + t);
    __builtin_nontemporal_store(res2, out + 2 * (size_t)N + t);
    __builtin_nontemporal_store(res3, out + 3 * (size_t)N + t);
}

extern "C" void kernel_launch(void* const* d_in, const int* in_sizes, int n_in,
                              void* d_out, int out_size, void* d_ws, size_t ws_size,
                              hipStream_t stream) {
    const float* audio = (const float*)d_in[0];
    const float* depth = (const float*)d_in[1];
    const float* rate  = (const float*)d_in[2];
    float* out = (float*)d_out;

    int N = in_sizes[0] / 4;               // B*C = 4 channels; N = 220500
    int threads = 256;
    int blocks = (N + threads - 1) / threads;  // 862
    Vibrato_90142773608915_kernel<<<blocks, threads, 0, stream>>>(audio, depth, rate, out, N);
}